// Round 6
// baseline (450.139 us; speedup 1.0000x reference)
//
#include <hip/hip_runtime.h>
#include <math.h>

#define NTOK (16 * 8192)   // 131072 tokens
#define H    256
#define E    32
#define SEQ  8192
#define BSZ  16
#define LPAD 33            // logit row stride: (tid*33+e)%32 = (tid+e)%32 -> conflict-free

// History: r0/r1 array accs -> scratch (556MB writes, 217us). r2 64 named accs:
// demoted to AGPR traffic (VGPR=56, 121us). r4 32 named accs + SGPR w: demoted
// again (VGPR=36, 202us). r5 expert-group tiling (8 accs): VALU finally clean
// (12% busy ~= ideal issue) BUT x re-read 4x -> FETCH_SIZE 470MB, fetch-bound
// at 2.7TB/s, 174us. r6: H-chunk tiling -- x read ONCE into 16 named float4
// regs per chunk; partial logits parked in private LDS rows between chunks;
// still only 8 accs live (the proven non-demoting shape); occupancy 2->4
// waves/SIMD via launch_bounds(256,4).

__device__ __forceinline__ float waveReduceSum(float v) {
#pragma unroll
    for (int off = 32; off > 0; off >>= 1) v += __shfl_xor(v, off, 64);
    return v;
}

// ---------------- zero the workspace accumulators ----------------
__global__ __launch_bounds__(256) void zero_ws_kernel(float* ws) {
    int i = blockIdx.x * 256 + threadIdx.x;
    if (i < BSZ * E * 2) ws[i] = 0.0f;
}

// 4 fmacs: expert K, h-subword J of this chunk, x register XV, into named ACC.
// wg + K*H + J*4 is wave-uniform (loop counters + literal) -> s_load_dwordx4.
#define W4(K, J, XV, ACC) { \
    const float4 wv = *(const float4*)(wg + (K) * H + (J) * 4); \
    ACC = fmaf(wv.x, XV.x, ACC); ACC = fmaf(wv.y, XV.y, ACC); \
    ACC = fmaf(wv.z, XV.z, ACC); ACC = fmaf(wv.w, XV.w, ACC); }

// One expert x one 64-h chunk: 16 uniform w loads, 64 fmac into one acc.
#define EX16(K, ACC) \
    W4(K, 0, x0, ACC)  W4(K, 1, x1, ACC)  W4(K, 2, x2, ACC)  W4(K, 3, x3, ACC) \
    W4(K, 4, x4, ACC)  W4(K, 5, x5, ACC)  W4(K, 6, x6, ACC)  W4(K, 7, x7, ACC) \
    W4(K, 8, x8, ACC)  W4(K, 9, x9, ACC)  W4(K,10, x10, ACC) W4(K,11, x11, ACC) \
    W4(K,12, x12, ACC) W4(K,13, x13, ACC) W4(K,14, x14, ACC) W4(K,15, x15, ACC)

// ---------------- main gate kernel ----------------
__global__ __launch_bounds__(256, 4) void gate_kernel(
    const float* __restrict__ x, const float* __restrict__ w,
    float* __restrict__ out, float* __restrict__ ws_cnt, float* __restrict__ ws_sum)
{
    __shared__ float logit_lds[256 * LPAD];   // 33.8KB: [tid][e], private rows
    __shared__ float s_sum[E];                // per-block aux aggregation
    __shared__ float s_cnt[E];

    const int tid   = threadIdx.x;
    const int lane  = tid & 63;
    const int token = blockIdx.x * 256 + tid;
    const float* xb = x + (size_t)token * H;
    float* lrow     = logit_lds + tid * LPAD;

    if (tid < E) { s_sum[tid] = 0.0f; s_cnt[tid] = 0.0f; }
    // zero own logit row (private -- no barrier needed for it)
#pragma unroll
    for (int e = 0; e < E; ++e) lrow[e] = 0.0f;
    __syncthreads();   // for s_sum/s_cnt only

    // ---- x read ONCE: 4 H-chunks; per chunk 16 float4 in flight (16KB/wave
    // latency cover), then 4 expert-group passes with 8 regs live, partials
    // accumulated through the private LDS row. ----
#pragma unroll 1
    for (int c = 0; c < 4; ++c) {
        const float* xc = xb + c * 64;
        const float4 x0  = *(const float4*)(xc +  0);
        const float4 x1  = *(const float4*)(xc +  4);
        const float4 x2  = *(const float4*)(xc +  8);
        const float4 x3  = *(const float4*)(xc + 12);
        const float4 x4  = *(const float4*)(xc + 16);
        const float4 x5  = *(const float4*)(xc + 20);
        const float4 x6  = *(const float4*)(xc + 24);
        const float4 x7  = *(const float4*)(xc + 28);
        const float4 x8  = *(const float4*)(xc + 32);
        const float4 x9  = *(const float4*)(xc + 36);
        const float4 x10 = *(const float4*)(xc + 40);
        const float4 x11 = *(const float4*)(xc + 44);
        const float4 x12 = *(const float4*)(xc + 48);
        const float4 x13 = *(const float4*)(xc + 52);
        const float4 x14 = *(const float4*)(xc + 56);
        const float4 x15 = *(const float4*)(xc + 60);

#pragma unroll 1
        for (int G = 0; G < 4; ++G) {
            const float* wg = w + (size_t)(G * 8) * H + c * 64;   // wave-uniform
            float* lp = lrow + G * 8;
            float b0 = lp[0], b1 = lp[1], b2 = lp[2], b3 = lp[3],
                  b4 = lp[4], b5 = lp[5], b6 = lp[6], b7 = lp[7];
            EX16(0, b0) EX16(1, b1) EX16(2, b2) EX16(3, b3)
            EX16(4, b4) EX16(5, b5) EX16(6, b6) EX16(7, b7)
            lp[0] = b0; lp[1] = b1; lp[2] = b2; lp[3] = b3;
            lp[4] = b4; lp[5] = b5; lp[6] = b6; lp[7] = b7;
        }
    }

    // ---- pass 1: max + argmax over my 32 logits (strict > = earliest index
    // on ties, matches top_k) ----
    float m  = -3.402823466e+38f;
    int   id = 0;
#pragma unroll
    for (int e = 0; e < E; ++e) {
        const float v = lrow[e];
        if (v > m) { m = v; id = e; }
    }

    // ---- pass 2: exp, store p back to LDS (reused by aux), sum ----
    float ss = 0.0f;
#pragma unroll
    for (int e = 0; e < E; ++e) {
        const float p = __expf(lrow[e] - m);
        lrow[e] = p;
        ss += p;
    }
    const float inv = 1.0f / ss;       // softmax score at argmax; SCALING = 1.0
    out[token]        = (float)id;
    out[NTOK + token] = inv;

    // ---- pass 3: aux-loss, streamed per expert: wave-reduce probs + ballot
    // counts, aggregate per block in LDS, one global atomic set per block ----
#pragma unroll
    for (int e = 0; e < E; ++e) {
        const float sc = waveReduceSum(lrow[e] * inv);
        const unsigned long long bl = __ballot(id == e);
        if (lane == 0) {
            atomicAdd(&s_sum[e], sc);
            if (bl) atomicAdd(&s_cnt[e], (float)__popcll(bl));
        }
    }

    __syncthreads();
    if (tid < E) {
        const int b = blockIdx.x >> 5;   // 256 tokens/block, 32 blocks/batch
        atomicAdd(&ws_sum[b * E + tid], s_sum[tid]);
        const float cn = s_cnt[tid];
        if (cn != 0.0f) atomicAdd(&ws_cnt[b * E + tid], cn);
    }
}

// ---------------- aux loss reduction ----------------
__global__ __launch_bounds__(256) void aux_kernel(
    const float* __restrict__ ws_cnt, const float* __restrict__ ws_sum,
    float* __restrict__ out)
{
    const int tid = threadIdx.x;
    float p = 0.0f;
    for (int i = tid; i < BSZ * E; i += 256)
        p += ws_cnt[i] * ws_sum[i];

    __shared__ float red[4];
#pragma unroll
    for (int off = 32; off > 0; off >>= 1)
        p += __shfl_xor(p, off, 64);
    if ((tid & 63) == 0) red[tid >> 6] = p;
    __syncthreads();
    if (tid == 0) {
        float t = red[0] + red[1] + red[2] + red[3];
        // aux = sum_be cnt*ssum * alpha / (B * (SEQ/E) * SEQ)
        out[2 * NTOK] = t * (0.001f / (16.0f * 256.0f * 8192.0f));
    }
}

extern "C" void kernel_launch(void* const* d_in, const int* in_sizes, int n_in,
                              void* d_out, int out_size, void* d_ws, size_t ws_size,
                              hipStream_t stream) {
    const float* x = (const float*)d_in[0];
    const float* w = (const float*)d_in[1];
    float* out    = (float*)d_out;
    float* ws     = (float*)d_ws;
    float* ws_cnt = ws;
    float* ws_sum = ws + BSZ * E;

    zero_ws_kernel<<<4, 256, 0, stream>>>(ws);
    gate_kernel<<<NTOK / 256, 256, 0, stream>>>(x, w, out, ws_cnt, ws_sum);
    aux_kernel<<<1, 256, 0, stream>>>(ws_cnt, ws_sum, out);
}

// Round 7
// 345.920 us; speedup vs baseline: 1.3013x; 1.3013x over previous
//
#include <hip/hip_runtime.h>
#include <math.h>

#define NTOK (16 * 8192)   // 131072 tokens
#define H    256
#define E    32
#define SEQ  8192
#define BSZ  16
#define LPAD 33            // logit row stride: bank (tid+e)%32 -> conflict-free
#define NBLK (NTOK / 256)  // 512 blocks

// History: r0/r1 array accs -> scratch (556MB wr). r2 64 named accs -> demoted.
// r4 32 accs + SGPR w -> demoted (VGPR=36). r5 expert-tiling, 16 s_loads per
// region: CLEAN VALU (12% ~= ideal) but x re-read 4x (FETCH 470MB). r6 x-once +
// 128 s_loads per region: scheduler hoisted them -> SGPR file blown -> scratch
// (WRITE 267MB). r7: x-once + 16-s_load regions fenced by sched_barrier(0) +
// waves_per_eu(2,2) (grid caps at 2 waves/SIMD anyway -> allocate for 2, not 8)
// + aux fused into gate via last-block-done counter (saves a dispatch).

#define SBAR() __builtin_amdgcn_sched_barrier(0)

__device__ __forceinline__ float waveReduceSum(float v) {
#pragma unroll
    for (int off = 32; off > 0; off >>= 1) v += __shfl_xor(v, off, 64);
    return v;
}

// ---------------- zero the workspace accumulators + done counter ----------------
__global__ __launch_bounds__(256) void zero_ws_kernel(float* ws) {
    int i = blockIdx.x * 256 + threadIdx.x;
    if (i < BSZ * E * 2 + 1) ws[i] = 0.0f;   // +1: done counter (bits 0)
}

// 8 fmacs: expert K of this group, h-substep S (8 floats), x regs XA,XB.
// wg + K*H + S*8 is wave-uniform -> s_load; 16 such loads per STEP region.
#define EXK(S, K, XA, XB, ACC) { \
    const float4 u = *(const float4*)(wg + (K) * H + (S) * 8);     \
    const float4 v = *(const float4*)(wg + (K) * H + (S) * 8 + 4); \
    ACC = fmaf(u.x, XA.x, ACC); ACC = fmaf(u.y, XA.y, ACC); \
    ACC = fmaf(u.z, XA.z, ACC); ACC = fmaf(u.w, XA.w, ACC); \
    ACC = fmaf(v.x, XB.x, ACC); ACC = fmaf(v.y, XB.y, ACC); \
    ACC = fmaf(v.z, XB.z, ACC); ACC = fmaf(v.w, XB.w, ACC); }

// One 8-h step x 8 experts: exactly 16 s_load_dwordx4 (64 SGPRs) + 64 fmacs,
// then a full sched_barrier so the NEXT step's loads cannot hoist into this
// region (the r6 SGPR-blowout killer).
#define STEP(S, XA, XB) \
    EXK(S, 0, XA, XB, b0) EXK(S, 1, XA, XB, b1) \
    EXK(S, 2, XA, XB, b2) EXK(S, 3, XA, XB, b3) \
    EXK(S, 4, XA, XB, b4) EXK(S, 5, XA, XB, b5) \
    EXK(S, 6, XA, XB, b6) EXK(S, 7, XA, XB, b7) \
    SBAR();

// ---------------- main gate kernel (aux reduction fused) ----------------
__global__ __launch_bounds__(256)
__attribute__((amdgpu_waves_per_eu(2, 2)))
void gate_kernel(
    const float* __restrict__ x, const float* __restrict__ w,
    float* __restrict__ out, float* __restrict__ ws)
{
    __shared__ float logit_lds[256 * LPAD];   // 33.8KB: [tid][e], private rows
    __shared__ float s_sum[E];                // per-block aux aggregation
    __shared__ float s_cnt[E];
    __shared__ float s_red[4];
    __shared__ unsigned s_last;

    float* __restrict__ ws_cnt = ws;
    float* __restrict__ ws_sum = ws + BSZ * E;
    unsigned* done = (unsigned*)(ws + 2 * BSZ * E);

    const int tid   = threadIdx.x;
    const int lane  = tid & 63;
    const int token = blockIdx.x * 256 + tid;
    const float* xb = x + (size_t)token * H;
    float* lrow     = logit_lds + tid * LPAD;

    if (tid < E) { s_sum[tid] = 0.0f; s_cnt[tid] = 0.0f; }
#pragma unroll
    for (int e = 0; e < E; ++e) lrow[e] = 0.0f;
    __syncthreads();   // for s_sum/s_cnt only (lrow is thread-private)

    // ---- x read ONCE: 4 H-chunks into 16 named float4 regs; per chunk,
    // 4 expert-groups with 8 accs live; partials via private LDS row ----
#pragma unroll 1
    for (int c = 0; c < 4; ++c) {
        const float* xc = xb + c * 64;
        const float4 x0  = *(const float4*)(xc +  0);
        const float4 x1  = *(const float4*)(xc +  4);
        const float4 x2  = *(const float4*)(xc +  8);
        const float4 x3  = *(const float4*)(xc + 12);
        const float4 x4  = *(const float4*)(xc + 16);
        const float4 x5  = *(const float4*)(xc + 20);
        const float4 x6  = *(const float4*)(xc + 24);
        const float4 x7  = *(const float4*)(xc + 28);
        const float4 x8  = *(const float4*)(xc + 32);
        const float4 x9  = *(const float4*)(xc + 36);
        const float4 x10 = *(const float4*)(xc + 40);
        const float4 x11 = *(const float4*)(xc + 44);
        const float4 x12 = *(const float4*)(xc + 48);
        const float4 x13 = *(const float4*)(xc + 52);
        const float4 x14 = *(const float4*)(xc + 56);
        const float4 x15 = *(const float4*)(xc + 60);

#pragma unroll 1
        for (int G = 0; G < 4; ++G) {
            const float* wg = w + (size_t)(G * 8) * H + c * 64;   // wave-uniform
            float* lp = lrow + G * 8;
            float b0 = lp[0], b1 = lp[1], b2 = lp[2], b3 = lp[3],
                  b4 = lp[4], b5 = lp[5], b6 = lp[6], b7 = lp[7];
            STEP(0, x0,  x1)  STEP(1, x2,  x3)
            STEP(2, x4,  x5)  STEP(3, x6,  x7)
            STEP(4, x8,  x9)  STEP(5, x10, x11)
            STEP(6, x12, x13) STEP(7, x14, x15)
            lp[0] = b0; lp[1] = b1; lp[2] = b2; lp[3] = b3;
            lp[4] = b4; lp[5] = b5; lp[6] = b6; lp[7] = b7;
        }
    }

    // ---- max + argmax (strict > = earliest index on ties, matches top_k) ----
    float m  = -3.402823466e+38f;
    int   id = 0;
#pragma unroll
    for (int e = 0; e < E; ++e) {
        const float v = lrow[e];
        if (v > m) { m = v; id = e; }
    }

    // ---- exp, park p in LDS (reused by aux), sum ----
    float ss = 0.0f;
#pragma unroll
    for (int e = 0; e < E; ++e) {
        const float p = __expf(lrow[e] - m);
        lrow[e] = p;
        ss += p;
    }
    const float inv = 1.0f / ss;       // softmax score at argmax; SCALING = 1.0
    out[token]        = (float)id;
    out[NTOK + token] = inv;

    // ---- aux: wave-reduce probs + ballot counts, per-block LDS aggregate ----
#pragma unroll
    for (int e = 0; e < E; ++e) {
        const float sc = waveReduceSum(lrow[e] * inv);
        const unsigned long long bl = __ballot(id == e);
        if (lane == 0) {
            atomicAdd(&s_sum[e], sc);
            if (bl) atomicAdd(&s_cnt[e], (float)__popcll(bl));
        }
    }

    __syncthreads();
    if (tid < E) {
        const int b = blockIdx.x >> 5;   // 256 tokens/block, 32 blocks/batch
        atomicAdd(&ws_sum[b * E + tid], s_sum[tid]);
        const float cn = s_cnt[tid];
        if (cn != 0.0f) atomicAdd(&ws_cnt[b * E + tid], cn);
    }

    // ---- fused final reduction: last block to finish computes aux loss ----
    __threadfence();     // all threads: make this block's atomics visible
    __syncthreads();
    if (tid == 0) {
        const unsigned old = atomicAdd(done, 1u);
        s_last = (old == (unsigned)(NBLK - 1)) ? 1u : 0u;
    }
    __syncthreads();
    if (s_last) {
        float p = 0.0f;
#pragma unroll
        for (int i = tid; i < BSZ * E; i += 256) {
            // device-scope coherent loads (other XCDs' atomics)
            const float c = __hip_atomic_load(&ws_cnt[i], __ATOMIC_RELAXED,
                                              __HIP_MEMORY_SCOPE_AGENT);
            const float s = __hip_atomic_load(&ws_sum[i], __ATOMIC_RELAXED,
                                              __HIP_MEMORY_SCOPE_AGENT);
            p += c * s;
        }
        p = waveReduceSum(p);
        if ((tid & 63) == 0) s_red[tid >> 6] = p;
        __syncthreads();
        if (tid == 0) {
            const float t = s_red[0] + s_red[1] + s_red[2] + s_red[3];
            // aux = sum_be cnt*ssum * alpha / (B * (SEQ/E) * SEQ)
            out[2 * NTOK] = t * (0.001f / (16.0f * 256.0f * 8192.0f));
        }
    }
}

extern "C" void kernel_launch(void* const* d_in, const int* in_sizes, int n_in,
                              void* d_out, int out_size, void* d_ws, size_t ws_size,
                              hipStream_t stream) {
    const float* x = (const float*)d_in[0];
    const float* w = (const float*)d_in[1];
    float* out = (float*)d_out;
    float* ws  = (float*)d_ws;

    zero_ws_kernel<<<5, 256, 0, stream>>>(ws);
    gate_kernel<<<NBLK, 256, 0, stream>>>(x, w, out, ws);
}

// Round 8
// 252.766 us; speedup vs baseline: 1.7808x; 1.3685x over previous
//
#include <hip/hip_runtime.h>
#include <math.h>

#define NTOK (16 * 8192)   // 131072 tokens
#define H    256
#define E    32
#define SEQ  8192
#define BSZ  16
#define LPAD 33            // logit row stride: bank (tid+e)%32 -> conflict-free
#define NBLK (NTOK / 256)  // 512 blocks

// History: r0/r1 array accs -> scratch (556MB wr). r2 w-LDS + 64 named accs:
// 121us (best) but accs demoted -> 4x VALU. r4/r5/r7 w-SGPR: 202/174/244us --
// EVERY scalar-path round is latency-bound (r7: VALU 21%, no memory traffic,
// 244us = s_load latency through the small shared scalar cache, serialized by
// per-step sched_barrier). r6: 128 s_loads/region -> SGPR blowout -> scratch.
// r8: w back in LDS (per-CU, ds_read broadcast, ~120cy pipelined latency) +
// the r5-proven 8-acc groups + r7's x-read-once + sched_barrier every 2 steps
// (bounds ds_read hoist to 32xb128 = 128 VGPR, no r6-class blowout).

#define SBAR() __builtin_amdgcn_sched_barrier(0)

__device__ __forceinline__ float waveReduceSum(float v) {
#pragma unroll
    for (int off = 32; off > 0; off >>= 1) v += __shfl_xor(v, off, 64);
    return v;
}

// ---------------- zero the workspace accumulators + done counter ----------------
__global__ __launch_bounds__(256) void zero_ws_kernel(float* ws) {
    int i = blockIdx.x * 256 + threadIdx.x;
    if (i < BSZ * E * 2 + 1) ws[i] = 0.0f;
}

// 16 fmacs: expert K of group, h-step S (8 floats), x regs XA,XB.
// wg + K*H + S*8 is wave-uniform -> ds_read_b128 broadcast (conflict-free).
#define EXK(S, K, XA, XB, ACC) { \
    const float4 u = *(const float4*)(wg + (K) * H + (S) * 8);     \
    const float4 v = *(const float4*)(wg + (K) * H + (S) * 8 + 4); \
    ACC = fmaf(u.x, XA.x, ACC); ACC = fmaf(u.y, XA.y, ACC); \
    ACC = fmaf(u.z, XA.z, ACC); ACC = fmaf(u.w, XA.w, ACC); \
    ACC = fmaf(v.x, XB.x, ACC); ACC = fmaf(v.y, XB.y, ACC); \
    ACC = fmaf(v.z, XB.z, ACC); ACC = fmaf(v.w, XB.w, ACC); }

// One 8-h step x 8 experts: 16 ds_read_b128 + 64 fmacs.
#define STEP(S, XA, XB) \
    EXK(S, 0, XA, XB, b0) EXK(S, 1, XA, XB, b1) \
    EXK(S, 2, XA, XB, b2) EXK(S, 3, XA, XB, b3) \
    EXK(S, 4, XA, XB, b4) EXK(S, 5, XA, XB, b5) \
    EXK(S, 6, XA, XB, b6) EXK(S, 7, XA, XB, b7)

// ---------------- main gate kernel (aux reduction fused) ----------------
__global__ __launch_bounds__(256, 2) void gate_kernel(
    const float* __restrict__ x, const float* __restrict__ w,
    float* __restrict__ out, float* __restrict__ ws)
{
    __shared__ float w_lds[E * H];            // 32KB, [e][h]
    __shared__ float logit_lds[256 * LPAD];   // 33.8KB: [tid][e], private rows
    __shared__ float s_sum[E];                // per-block aux aggregation
    __shared__ float s_cnt[E];
    __shared__ float s_red[4];
    __shared__ unsigned s_last;

    float* __restrict__ ws_cnt = ws;
    float* __restrict__ ws_sum = ws + BSZ * E;
    unsigned* done = (unsigned*)(ws + 2 * BSZ * E);

    const int tid   = threadIdx.x;
    const int lane  = tid & 63;
    const int token = blockIdx.x * 256 + tid;
    const float* xb = x + (size_t)token * H;
    float* lrow     = logit_lds + tid * LPAD;

    // ---- stage w into LDS (coalesced float4: 8 per thread) ----
    {
        float4*       wl = (float4*)w_lds;
        const float4* wgl = (const float4*)w;
#pragma unroll
        for (int i = 0; i < (E * H / 4) / 256; ++i)
            wl[tid + 256 * i] = wgl[tid + 256 * i];
    }
    if (tid < E) { s_sum[tid] = 0.0f; s_cnt[tid] = 0.0f; }
#pragma unroll
    for (int e = 0; e < E; ++e) lrow[e] = 0.0f;   // private row, but barrier below
    __syncthreads();   // w_lds + s_sum/s_cnt ready

    // ---- x read ONCE: 4 H-chunks into 16 named float4 regs; per chunk,
    // 4 expert-groups with 8 accs live (non-demoting shape); partials parked
    // in private LDS rows between chunks ----
#pragma unroll 1
    for (int c = 0; c < 4; ++c) {
        const float* xc = xb + c * 64;
        const float4 x0  = *(const float4*)(xc +  0);
        const float4 x1  = *(const float4*)(xc +  4);
        const float4 x2  = *(const float4*)(xc +  8);
        const float4 x3  = *(const float4*)(xc + 12);
        const float4 x4  = *(const float4*)(xc + 16);
        const float4 x5  = *(const float4*)(xc + 20);
        const float4 x6  = *(const float4*)(xc + 24);
        const float4 x7  = *(const float4*)(xc + 28);
        const float4 x8  = *(const float4*)(xc + 32);
        const float4 x9  = *(const float4*)(xc + 36);
        const float4 x10 = *(const float4*)(xc + 40);
        const float4 x11 = *(const float4*)(xc + 44);
        const float4 x12 = *(const float4*)(xc + 48);
        const float4 x13 = *(const float4*)(xc + 52);
        const float4 x14 = *(const float4*)(xc + 56);
        const float4 x15 = *(const float4*)(xc + 60);

#pragma unroll 1
        for (int G = 0; G < 4; ++G) {
            const float* wg = w_lds + (G * 8) * H + c * 64;   // wave-uniform LDS
            float* lp = lrow + G * 8;
            float b0 = lp[0], b1 = lp[1], b2 = lp[2], b3 = lp[3],
                  b4 = lp[4], b5 = lp[5], b6 = lp[6], b7 = lp[7];
            // barrier every 2 steps: caps ds_read hoist at 32 b128 (128 VGPR)
            STEP(0, x0,  x1)  STEP(1, x2,  x3)  SBAR();
            STEP(2, x4,  x5)  STEP(3, x6,  x7)  SBAR();
            STEP(4, x8,  x9)  STEP(5, x10, x11) SBAR();
            STEP(6, x12, x13) STEP(7, x14, x15)
            lp[0] = b0; lp[1] = b1; lp[2] = b2; lp[3] = b3;
            lp[4] = b4; lp[5] = b5; lp[6] = b6; lp[7] = b7;
        }
    }

    // ---- max + argmax (strict > = earliest index on ties, matches top_k) ----
    float m  = -3.402823466e+38f;
    int   id = 0;
#pragma unroll
    for (int e = 0; e < E; ++e) {
        const float v = lrow[e];
        if (v > m) { m = v; id = e; }
    }

    // ---- exp, park p in LDS (reused by aux), sum ----
    float ss = 0.0f;
#pragma unroll
    for (int e = 0; e < E; ++e) {
        const float p = __expf(lrow[e] - m);
        lrow[e] = p;
        ss += p;
    }
    const float inv = 1.0f / ss;       // softmax score at argmax; SCALING = 1.0
    out[token]        = (float)id;
    out[NTOK + token] = inv;

    // ---- aux: wave-reduce probs + ballot counts, per-block LDS aggregate ----
#pragma unroll
    for (int e = 0; e < E; ++e) {
        const float sc = waveReduceSum(lrow[e] * inv);
        const unsigned long long bl = __ballot(id == e);
        if (lane == 0) {
            atomicAdd(&s_sum[e], sc);
            if (bl) atomicAdd(&s_cnt[e], (float)__popcll(bl));
        }
    }

    __syncthreads();
    if (tid < E) {
        const int b = blockIdx.x >> 5;   // 256 tokens/block, 32 blocks/batch
        atomicAdd(&ws_sum[b * E + tid], s_sum[tid]);
        const float cn = s_cnt[tid];
        if (cn != 0.0f) atomicAdd(&ws_cnt[b * E + tid], cn);
    }

    // ---- fused final reduction: last block to finish computes aux loss ----
    __threadfence();     // make this block's atomics visible device-wide
    __syncthreads();
    if (tid == 0) {
        const unsigned old = atomicAdd(done, 1u);
        s_last = (old == (unsigned)(NBLK - 1)) ? 1u : 0u;
    }
    __syncthreads();
    if (s_last) {
        float p = 0.0f;
#pragma unroll
        for (int i = tid; i < BSZ * E; i += 256) {
            // device-scope coherent loads (other XCDs' atomics)
            const float c = __hip_atomic_load(&ws_cnt[i], __ATOMIC_RELAXED,
                                              __HIP_MEMORY_SCOPE_AGENT);
            const float s = __hip_atomic_load(&ws_sum[i], __ATOMIC_RELAXED,
                                              __HIP_MEMORY_SCOPE_AGENT);
            p += c * s;
        }
        p = waveReduceSum(p);
        if ((tid & 63) == 0) s_red[tid >> 6] = p;
        __syncthreads();
        if (tid == 0) {
            const float t = s_red[0] + s_red[1] + s_red[2] + s_red[3];
            // aux = sum_be cnt*ssum * alpha / (B * (SEQ/E) * SEQ)
            out[2 * NTOK] = t * (0.001f / (16.0f * 256.0f * 8192.0f));
        }
    }
}

extern "C" void kernel_launch(void* const* d_in, const int* in_sizes, int n_in,
                              void* d_out, int out_size, void* d_ws, size_t ws_size,
                              hipStream_t stream) {
    const float* x = (const float*)d_in[0];
    const float* w = (const float*)d_in[1];
    float* out = (float*)d_out;
    float* ws  = (float*)d_ws;

    zero_ws_kernel<<<5, 256, 0, stream>>>(ws);
    gate_kernel<<<NBLK, 256, 0, stream>>>(x, w, out, ws);
}

// Round 9
// 238.586 us; speedup vs baseline: 1.8867x; 1.0594x over previous
//
#include <hip/hip_runtime.h>
#include <math.h>

#define NTOK (16 * 8192)   // 131072 tokens
#define H    256
#define E    32
#define SEQ  8192
#define BSZ  16
#define NBLK 256           // 512 tokens/block (T=2), 1 block/CU

// History: r0-r7: every w-path tried. LDS-broadcast (r2/r8): per-CU LDS pipe
// must deliver waves*32KB -> ~16K b128 ops/CU at ~12-17cy = the 120us wall.
// SGPR s_load (r4/r5/r7): shared scalar-cache thrash, 174-244us. r9: w in
// per-lane VGPRs (32 named float4/lane: lane l owns expert l>>1, half l&1),
// broadcast via v_readlane (VALU pipe, no memory). T=2 tokens/thread halves
// broadcasts/fmac. 4-expert groups (8 accs, proven non-demoting); partials
// park in XOR-swizzled float4 LDS rows (conflict-free, ~256 ops/thread).

__device__ __forceinline__ float waveReduceSum(float v) {
#pragma unroll
    for (int off = 32; off > 0; off >>= 1) v += __shfl_xor(v, off, 64);
    return v;
}

// ---------------- zero the workspace accumulators + done counter ----------------
__global__ __launch_bounds__(256) void zero_ws_kernel(float* ws) {
    int i = blockIdx.x * 256 + threadIdx.x;
    if (i < BSZ * E * 2 + 1) ws[i] = 0.0f;
}

#define RL(V, S) __int_as_float(__builtin_amdgcn_readlane(__float_as_int(V), (S)))

// One w-float4 (register WR of source lanes) x 4 experts (k: src0+2k) x 2 tokens:
// 16 readlane (SGPR results) + 32 v_fmac (SGPR operand legal: 1 per VALU op).
#define BC1(WR, K, XA, XB) { \
    const int s_ = src0 + 2 * (K); \
    float t_; \
    t_ = RL(WR.x, s_); a##K = fmaf(t_, XA.x, a##K); b##K = fmaf(t_, XB.x, b##K); \
    t_ = RL(WR.y, s_); a##K = fmaf(t_, XA.y, a##K); b##K = fmaf(t_, XB.y, b##K); \
    t_ = RL(WR.z, s_); a##K = fmaf(t_, XA.z, a##K); b##K = fmaf(t_, XB.z, b##K); \
    t_ = RL(WR.w, s_); a##K = fmaf(t_, XA.w, a##K); b##K = fmaf(t_, XB.w, b##K); }

#define BCJ(WR, XA, XB) BC1(WR,0,XA,XB) BC1(WR,1,XA,XB) BC1(WR,2,XA,XB) BC1(WR,3,XA,XB)

// One 32-h quarter-section (static Q -> static W regs P0..P7): load x chunk,
// then 8 group-passes (runtime g -> runtime SOURCE LANE, static registers).
#define QSEC(P0,P1,P2,P3,P4,P5,P6,P7, Q, FIRSTC) { \
    const int hb_ = cc * 128 + (Q) * 32; \
    const float4 cA0 = *(const float4*)(xA + hb_ +  0); \
    const float4 cA1 = *(const float4*)(xA + hb_ +  4); \
    const float4 cA2 = *(const float4*)(xA + hb_ +  8); \
    const float4 cA3 = *(const float4*)(xA + hb_ + 12); \
    const float4 cA4 = *(const float4*)(xA + hb_ + 16); \
    const float4 cA5 = *(const float4*)(xA + hb_ + 20); \
    const float4 cA6 = *(const float4*)(xA + hb_ + 24); \
    const float4 cA7 = *(const float4*)(xA + hb_ + 28); \
    const float4 cB0 = *(const float4*)(xB + hb_ +  0); \
    const float4 cB1 = *(const float4*)(xB + hb_ +  4); \
    const float4 cB2 = *(const float4*)(xB + hb_ +  8); \
    const float4 cB3 = *(const float4*)(xB + hb_ + 12); \
    const float4 cB4 = *(const float4*)(xB + hb_ + 16); \
    const float4 cB5 = *(const float4*)(xB + hb_ + 20); \
    const float4 cB6 = *(const float4*)(xB + hb_ + 24); \
    const float4 cB7 = *(const float4*)(xB + hb_ + 28); \
    _Pragma("unroll 1") \
    for (int g = 0; g < 8; ++g) { \
        const int src0 = 8 * g + cc;          /* src lane = 2e+half, e=4g+k */ \
        const int sA = (2 * g) ^ sw, sB = (2 * g + 1) ^ sw; \
        float a0, a1, a2, a3, b0, b1, b2, b3; \
        if (FIRSTC) { a0=a1=a2=a3=b0=b1=b2=b3=0.0f; } \
        else { \
            const float4 pa = mypark[sA], pb = mypark[sB]; \
            a0=pa.x; a1=pa.y; a2=pa.z; a3=pa.w; \
            b0=pb.x; b1=pb.y; b2=pb.z; b3=pb.w; \
        } \
        BCJ(P0, cA0, cB0) BCJ(P1, cA1, cB1) BCJ(P2, cA2, cB2) BCJ(P3, cA3, cB3) \
        BCJ(P4, cA4, cB4) BCJ(P5, cA5, cB5) BCJ(P6, cA6, cB6) BCJ(P7, cA7, cB7) \
        mypark[sA] = make_float4(a0, a1, a2, a3); \
        mypark[sB] = make_float4(b0, b1, b2, b3); \
    } }

// ---------------- main gate kernel (aux reduction fused) ----------------
__global__ __launch_bounds__(256, 1) void gate_kernel(
    const float* __restrict__ x, const float* __restrict__ w,
    float* __restrict__ out, float* __restrict__ ws)
{
    __shared__ float4 park[256 * 16];   // 64KB: 16 f4 slots/thread, XOR-swizzled
    __shared__ float s_sum[E], s_cnt[E], s_red[4];
    __shared__ unsigned s_last;

    float* ws_cnt = ws;
    float* ws_sum = ws + BSZ * E;
    unsigned* done = (unsigned*)(ws + 2 * BSZ * E);

    const int tid  = threadIdx.x;
    const int lane = tid & 63;
    const int tokA = blockIdx.x * 512 + tid;   // tokB = tokA + 256, same batch
    const float* xA = x + (size_t)tokA * H;
    const float* xB = xA + 256 * H;
    const int sw   = tid & 15;                 // f4-slot XOR swizzle -> conflict-free
    float4* mypark = park + tid * 16;

    // ---- per-lane w ownership: lane l holds w[l>>1][(l&1)*128 ..+128) = 32 f4
    const float4* wme = (const float4*)(w + (size_t)(lane >> 1) * H + (lane & 1) * 128);
    const float4 W0  = wme[0],  W1  = wme[1],  W2  = wme[2],  W3  = wme[3];
    const float4 W4  = wme[4],  W5  = wme[5],  W6  = wme[6],  W7  = wme[7];
    const float4 W8  = wme[8],  W9  = wme[9],  W10 = wme[10], W11 = wme[11];
    const float4 W12 = wme[12], W13 = wme[13], W14 = wme[14], W15 = wme[15];
    const float4 W16 = wme[16], W17 = wme[17], W18 = wme[18], W19 = wme[19];
    const float4 W20 = wme[20], W21 = wme[21], W22 = wme[22], W23 = wme[23];
    const float4 W24 = wme[24], W25 = wme[25], W26 = wme[26], W27 = wme[27];
    const float4 W28 = wme[28], W29 = wme[29], W30 = wme[30], W31 = wme[31];

    if (tid < E) { s_sum[tid] = 0.0f; s_cnt[tid] = 0.0f; }
    __syncthreads();

    // ---- main loop: 2 h-halves (runtime) x 4 static 32-h quarters ----
#pragma unroll 1
    for (int cc = 0; cc < 2; ++cc) {
        QSEC(W0, W1, W2, W3, W4, W5, W6, W7,     0, (cc == 0))
        QSEC(W8, W9, W10,W11,W12,W13,W14,W15,    1, 0)
        QSEC(W16,W17,W18,W19,W20,W21,W22,W23,    2, 0)
        QSEC(W24,W25,W26,W27,W28,W29,W30,W31,    3, 0)
    }

    // ---- epilogue: read back both tokens' 32 logits (own rows, no barrier) ----
#define LDQ(g) float4 qA##g = mypark[(2*(g)) ^ sw]; float4 qB##g = mypark[(2*(g)+1) ^ sw];
    LDQ(0) LDQ(1) LDQ(2) LDQ(3) LDQ(4) LDQ(5) LDQ(6) LDQ(7)

#define AMX4(Q, BASE, M, ID) \
    if (Q.x > M) { M = Q.x; ID = (BASE); } \
    if (Q.y > M) { M = Q.y; ID = (BASE)+1; } \
    if (Q.z > M) { M = Q.z; ID = (BASE)+2; } \
    if (Q.w > M) { M = Q.w; ID = (BASE)+3; }

    float mA = -3.402823466e+38f; int idA = 0;
    AMX4(qA0, 0,mA,idA) AMX4(qA1, 4,mA,idA) AMX4(qA2, 8,mA,idA) AMX4(qA3,12,mA,idA)
    AMX4(qA4,16,mA,idA) AMX4(qA5,20,mA,idA) AMX4(qA6,24,mA,idA) AMX4(qA7,28,mA,idA)
    float mB = -3.402823466e+38f; int idB = 0;
    AMX4(qB0, 0,mB,idB) AMX4(qB1, 4,mB,idB) AMX4(qB2, 8,mB,idB) AMX4(qB3,12,mB,idB)
    AMX4(qB4,16,mB,idB) AMX4(qB5,20,mB,idB) AMX4(qB6,24,mB,idB) AMX4(qB7,28,mB,idB)

#define EXP4(Q, M, SS) \
    Q.x = __expf(Q.x - (M)); SS += Q.x; \
    Q.y = __expf(Q.y - (M)); SS += Q.y; \
    Q.z = __expf(Q.z - (M)); SS += Q.z; \
    Q.w = __expf(Q.w - (M)); SS += Q.w;

    float ssA = 0.0f;
    EXP4(qA0,mA,ssA) EXP4(qA1,mA,ssA) EXP4(qA2,mA,ssA) EXP4(qA3,mA,ssA)
    EXP4(qA4,mA,ssA) EXP4(qA5,mA,ssA) EXP4(qA6,mA,ssA) EXP4(qA7,mA,ssA)
    float ssB = 0.0f;
    EXP4(qB0,mB,ssB) EXP4(qB1,mB,ssB) EXP4(qB2,mB,ssB) EXP4(qB3,mB,ssB)
    EXP4(qB4,mB,ssB) EXP4(qB5,mB,ssB) EXP4(qB6,mB,ssB) EXP4(qB7,mB,ssB)

    const float invA = 1.0f / ssA, invB = 1.0f / ssB;   // SCALING = 1.0
    const int tokB = tokA + 256;
    out[tokA]        = (float)idA;
    out[NTOK + tokA] = invA;
    out[tokB]        = (float)idB;
    out[NTOK + tokB] = invB;

    // ---- aux: wave-reduce probs (both tokens) + ballot counts ----
#define AXC(QA, QB, C, e) { \
    float pc = QA.C * invA + QB.C * invB; \
    pc = waveReduceSum(pc); \
    const unsigned long long blA = __ballot(idA == (e)); \
    const unsigned long long blB = __ballot(idB == (e)); \
    if (lane == 0) { \
        atomicAdd(&s_sum[(e)], pc); \
        const float cn = (float)(__popcll(blA) + __popcll(blB)); \
        if (cn != 0.0f) atomicAdd(&s_cnt[(e)], cn); \
    } }
#define AX4(g) AXC(qA##g,qB##g,x,(g)*4) AXC(qA##g,qB##g,y,(g)*4+1) \
               AXC(qA##g,qB##g,z,(g)*4+2) AXC(qA##g,qB##g,w,(g)*4+3)
    AX4(0) AX4(1) AX4(2) AX4(3) AX4(4) AX4(5) AX4(6) AX4(7)

    __syncthreads();
    if (tid < E) {
        const int b = blockIdx.x >> 4;   // 512 tokens/block, 16 blocks/batch
        atomicAdd(&ws_sum[b * E + tid], s_sum[tid]);
        const float cn = s_cnt[tid];
        if (cn != 0.0f) atomicAdd(&ws_cnt[b * E + tid], cn);
    }

    // ---- fused final reduction: last block computes aux loss ----
    __threadfence();
    __syncthreads();
    if (tid == 0) {
        const unsigned old = atomicAdd(done, 1u);
        s_last = (old == (unsigned)(NBLK - 1)) ? 1u : 0u;
    }
    __syncthreads();
    if (s_last) {
        float p = 0.0f;
#pragma unroll
        for (int i = tid; i < BSZ * E; i += 256) {
            const float c = __hip_atomic_load(&ws_cnt[i], __ATOMIC_RELAXED,
                                              __HIP_MEMORY_SCOPE_AGENT);
            const float s = __hip_atomic_load(&ws_sum[i], __ATOMIC_RELAXED,
                                              __HIP_MEMORY_SCOPE_AGENT);
            p += c * s;
        }
        p = waveReduceSum(p);
        if ((tid & 63) == 0) s_red[tid >> 6] = p;
        __syncthreads();
        if (tid == 0) {
            const float t = s_red[0] + s_red[1] + s_red[2] + s_red[3];
            // aux = sum_be cnt*ssum * alpha / (B * (SEQ/E) * SEQ)
            out[2 * NTOK] = t * (0.001f / (16.0f * 256.0f * 8192.0f));
        }
    }
}

extern "C" void kernel_launch(void* const* d_in, const int* in_sizes, int n_in,
                              void* d_out, int out_size, void* d_ws, size_t ws_size,
                              hipStream_t stream) {
    const float* x = (const float*)d_in[0];
    const float* w = (const float*)d_in[1];
    float* out = (float*)d_out;
    float* ws  = (float*)d_ws;

    zero_ws_kernel<<<5, 256, 0, stream>>>(ws);
    gate_kernel<<<NBLK, 256, 0, stream>>>(x, w, out, ws);
}